// Round 12
// baseline (3631.506 us; speedup 1.0000x reference)
//
#include <hip/hip_runtime.h>

typedef __attribute__((ext_vector_type(4))) float  f32x4;
typedef __attribute__((ext_vector_type(2))) float  f32x2;
typedef __attribute__((ext_vector_type(8))) __bf16 bf16x8;
typedef __attribute__((ext_vector_type(4))) short  s16x4;
typedef __attribute__((ext_vector_type(8))) short  s16x8;
typedef unsigned char uchar;

__device__ __forceinline__ unsigned short f2bf(float f) {
  unsigned u = __builtin_bit_cast(unsigned, f);
  u += 0x7FFFu + ((u >> 16) & 1u);
  return (unsigned short)(u >> 16);
}
__device__ __forceinline__ float b2f(short s) {
  return __builtin_bit_cast(float, (unsigned)((unsigned short)s) << 16);
}
__device__ __forceinline__ float gelu_fast(float v) {
  float u = v * (0.7978845608f + 0.0356774081f * v * v);
  float t = __expf(-2.f * fabsf(u));
  float th = (1.f - t) / (1.f + t);
  th = (u >= 0.f) ? th : -th;
  return 0.5f * v * (1.f + th);
}

__device__ __forceinline__ void gload16(const void* g, void* l) {
  __builtin_amdgcn_global_load_lds(
      (const __attribute__((address_space(1))) void*)g,
      (__attribute__((address_space(3))) void*)l, 16, 0, 0);
}

// Transpose + cast weights: W [L][In][Out] f32 -> WT [L][Out][In] bf16
__global__ __launch_bounds__(256) void wcast(const float* __restrict__ W,
                                             short* __restrict__ WT,
                                             int In, int Out) {
  int i = blockIdx.x * 256 + threadIdx.x;
  int lay = blockIdx.y;
  if (i >= In * Out) return;
  const float* w = W + (size_t)lay * In * Out;
  short* wt = WT + (size_t)lay * In * Out;
  int ii = i % In, oo = i / In;
  wt[(size_t)oo * In + ii] = (short)f2bf(w[(size_t)ii * Out + oo]);
}

// LayerNorm over C=256, one wave per row, write bf16
__global__ __launch_bounds__(256) void ln_k(const float* __restrict__ x,
                                            const float* __restrict__ g,
                                            const float* __restrict__ b,
                                            short* __restrict__ out) {
  int row = blockIdx.x * 4 + (threadIdx.x >> 6);
  int l = threadIdx.x & 63;
  const float4 v = *(const float4*)(x + (size_t)row * 256 + l * 4);
  float s  = v.x + v.y + v.z + v.w;
  float ss = v.x * v.x + v.y * v.y + v.z * v.z + v.w * v.w;
#pragma unroll
  for (int o = 32; o >= 1; o >>= 1) {
    s  += __shfl_xor(s, o);
    ss += __shfl_xor(ss, o);
  }
  float mean = s * (1.0f / 256.0f);
  float var  = ss * (1.0f / 256.0f) - mean * mean;
  float rstd = rsqrtf(var + 1e-5f);
  const float4 gg = *(const float4*)(g + l * 4);
  const float4 bb = *(const float4*)(b + l * 4);
  s16x4 o4;
  o4[0] = (short)f2bf((v.x - mean) * rstd * gg.x + bb.x);
  o4[1] = (short)f2bf((v.y - mean) * rstd * gg.y + bb.y);
  o4[2] = (short)f2bf((v.z - mean) * rstd * gg.z + bb.z);
  o4[3] = (short)f2bf((v.w - mean) * rstd * gg.w + bb.w);
  *(s16x4*)(out + (size_t)row * 256 + l * 4) = o4;
}

// KNN attention: one wave per point. q bf16 [N][256], k8/v8 fp8 [N][256]
__global__ __launch_bounds__(256) void attn_k(const short* __restrict__ q_,
                                              const uchar* __restrict__ k8,
                                              const uchar* __restrict__ v8,
                                              const int* __restrict__ knn,
                                              short* __restrict__ out) {
  int n = blockIdx.x * 4 + (threadIdx.x >> 6);
  int l = threadIdx.x & 63;
  int j = l & 15, g = l >> 4;
  int idxj = knn[(size_t)n * 16 + j];
  const short* qp = q_ + (size_t)n * 256 + g * 64;
  const uchar* kp = k8 + (size_t)idxj * 256 + g * 64;
  float partial = 0.f;
#pragma unroll
  for (int t = 0; t < 4; ++t) {  // 16 channels per t
    int4 kv = *(const int4*)(kp + t * 16);
    s16x8 q0 = *(const s16x8*)(qp + t * 16);
    s16x8 q1 = *(const s16x8*)(qp + t * 16 + 8);
    f32x2 a;
    a = __builtin_amdgcn_cvt_pk_f32_fp8(kv.x, false);
    partial += a[0] * b2f(q0[0]) + a[1] * b2f(q0[1]);
    a = __builtin_amdgcn_cvt_pk_f32_fp8(kv.x, true);
    partial += a[0] * b2f(q0[2]) + a[1] * b2f(q0[3]);
    a = __builtin_amdgcn_cvt_pk_f32_fp8(kv.y, false);
    partial += a[0] * b2f(q0[4]) + a[1] * b2f(q0[5]);
    a = __builtin_amdgcn_cvt_pk_f32_fp8(kv.y, true);
    partial += a[0] * b2f(q0[6]) + a[1] * b2f(q0[7]);
    a = __builtin_amdgcn_cvt_pk_f32_fp8(kv.z, false);
    partial += a[0] * b2f(q1[0]) + a[1] * b2f(q1[1]);
    a = __builtin_amdgcn_cvt_pk_f32_fp8(kv.z, true);
    partial += a[0] * b2f(q1[2]) + a[1] * b2f(q1[3]);
    a = __builtin_amdgcn_cvt_pk_f32_fp8(kv.w, false);
    partial += a[0] * b2f(q1[4]) + a[1] * b2f(q1[5]);
    a = __builtin_amdgcn_cvt_pk_f32_fp8(kv.w, true);
    partial += a[0] * b2f(q1[6]) + a[1] * b2f(q1[7]);
  }
  partial += __shfl_xor(partial, 16);
  partial += __shfl_xor(partial, 32);
  float score = partial * 0.0625f;  // C^-0.5, C=256
  float mx = score;
#pragma unroll
  for (int o = 1; o < 16; o <<= 1) mx = fmaxf(mx, __shfl_xor(mx, o));
  float e = __expf(score - mx);
  float sum = e;
#pragma unroll
  for (int o = 1; o < 16; o <<= 1) sum += __shfl_xor(sum, o);
  float attn = e / sum;
  float4 o4 = {0.f, 0.f, 0.f, 0.f};
#pragma unroll
  for (int jj = 0; jj < 16; ++jj) {
    float aj = __shfl(attn, jj);
    int   ij = __shfl(idxj, jj);
    int vv = *(const int*)(v8 + (size_t)ij * 256 + l * 4);
    f32x2 lo = __builtin_amdgcn_cvt_pk_f32_fp8(vv, false);
    f32x2 hi = __builtin_amdgcn_cvt_pk_f32_fp8(vv, true);
    o4.x += aj * lo[0];
    o4.y += aj * lo[1];
    o4.z += aj * hi[0];
    o4.w += aj * hi[1];
  }
  s16x4 ob;
  ob[0] = (short)f2bf(o4.x);
  ob[1] = (short)f2bf(o4.y);
  ob[2] = (short)f2bf(o4.z);
  ob[3] = (short)f2bf(o4.w);
  *(s16x4*)(out + (size_t)n * 256 + l * 4) = ob;
}

// GEMM: A [M][KD] bf16 x BT [Nout][KD] bf16 -> out [M][Nout]
// EPI 1: +bias +resid(f32) -> f32.  EPI 3: qkv split -> q bf16 / k8 / v8 fp8
// (LDS-transpose epilogue, coalesced packed stores).
// 128x128 tile, BK=64, 4 waves (2x2), T2 XOR swizzle, T1 XCD-chunked swizzle.
template <int EPI, int KD>
__global__ __launch_bounds__(256) void gemm_k(
    const short* __restrict__ A, const short* __restrict__ BT,
    const float* __restrict__ bias, const float* __restrict__ resid,
    short* __restrict__ outb, float* __restrict__ outf,
    uchar* __restrict__ k8, uchar* __restrict__ v8, int Nout, int gx) {
  __shared__ __align__(16) char pool[36864];
  short* lA = (short*)pool;
  short* lB = (short*)(pool + 16384);
  const int tid = threadIdx.x;
  const int l = tid & 63, w = tid >> 6;
  const int nwg = gridDim.x;
  const int bid = blockIdx.x;
  const int swz = (bid & 7) * (nwg >> 3) + (bid >> 3);
  const int m0 = (swz / gx) << 7, n0 = (swz % gx) << 7;
  const int wm = w >> 1, wn = w & 1;

  f32x4 acc[4][4];
#pragma unroll
  for (int i = 0; i < 4; ++i)
#pragma unroll
    for (int jj = 0; jj < 4; ++jj) acc[i][jj] = f32x4{0.f, 0.f, 0.f, 0.f};

  const int srow = (w << 3) + (l >> 3);
  const int scol = (((l & 7) << 3)) ^ ((srow & 7) << 3);
  const short* gA = A + (size_t)(m0 + srow) * KD + scol;
  const short* gB = BT + (size_t)(n0 + srow) * KD + scol;

  for (int kt = 0; kt < KD; kt += 64) {
#pragma unroll
    for (int it = 0; it < 4; ++it) {
      gload16(gA + (size_t)(it * 32) * KD + kt, &lA[(it * 32 + w * 8) * 64]);
      gload16(gB + (size_t)(it * 32) * KD + kt, &lB[(it * 32 + w * 8) * 64]);
    }
    __syncthreads();
#pragma unroll
    for (int kc = 0; kc < 2; ++kc) {
      bf16x8 aF[4], bF[4];
#pragma unroll
      for (int f = 0; f < 4; ++f) {
        int r = wm * 64 + f * 16 + (l & 15);
        int ce = (kc * 32 + ((l >> 4) << 3)) ^ ((r & 7) << 3);
        aF[f] = *(const bf16x8*)(lA + r * 64 + ce);
      }
#pragma unroll
      for (int f = 0; f < 4; ++f) {
        int r = wn * 64 + f * 16 + (l & 15);
        int ce = (kc * 32 + ((l >> 4) << 3)) ^ ((r & 7) << 3);
        bF[f] = *(const bf16x8*)(lB + r * 64 + ce);
      }
#pragma unroll
      for (int mf = 0; mf < 4; ++mf)
#pragma unroll
        for (int nf = 0; nf < 4; ++nf)
          acc[mf][nf] = __builtin_amdgcn_mfma_f32_16x16x32_bf16(
              aF[mf], bF[nf], acc[mf][nf], 0, 0, 0);
    }
    __syncthreads();
  }

  const int lr = (l >> 4) << 2, lc = l & 15;
  if (EPI == 1) {
#pragma unroll
    for (int mf = 0; mf < 4; ++mf) {
#pragma unroll
      for (int nf = 0; nf < 4; ++nf) {
#pragma unroll
        for (int jj = 0; jj < 4; ++jj) {
          int row = m0 + wm * 64 + mf * 16 + lr + jj;
          int col = n0 + wn * 64 + nf * 16 + lc;
          float v = acc[mf][nf][jj] + bias[col] + resid[(size_t)row * 256 + col];
          outf[(size_t)row * 256 + col] = v;
        }
      }
    }
    return;
  }

  // EPI 3: wave-private LDS transpose -> coalesced packed stores.
  short* myL = (short*)(pool + w * 9216);
#pragma unroll
  for (int mf = 0; mf < 4; ++mf) {
#pragma unroll
    for (int nf = 0; nf < 4; ++nf) {
#pragma unroll
      for (int jj = 0; jj < 4; ++jj) {
        int rl = mf * 16 + lr + jj;
        int cl = nf * 16 + lc;
        myL[rl * 72 + cl] = (short)f2bf(acc[mf][nf][jj]);
      }
    }
  }
#pragma unroll
  for (int it = 0; it < 8; ++it) {
    int rl = it * 8 + (l >> 3);
    int cl = (l & 7) * 8;
    s16x8 vv = *(const s16x8*)(myL + rl * 72 + cl);
    int rowg = m0 + wm * 64 + rl;
    int colg = n0 + wn * 64 + cl;
    if (colg < 256) {
      *(s16x8*)(outb + (size_t)rowg * 256 + colg) = vv;
    } else {
      unsigned w0 = __builtin_amdgcn_cvt_pk_fp8_f32(b2f(vv[0]), b2f(vv[1]), 0, false);
      w0 = __builtin_amdgcn_cvt_pk_fp8_f32(b2f(vv[2]), b2f(vv[3]), w0, true);
      unsigned w1 = __builtin_amdgcn_cvt_pk_fp8_f32(b2f(vv[4]), b2f(vv[5]), 0, false);
      w1 = __builtin_amdgcn_cvt_pk_fp8_f32(b2f(vv[6]), b2f(vv[7]), w1, true);
      int2 pk = make_int2((int)w0, (int)w1);
      uchar* dst = (colg < 512) ? (k8 + (size_t)rowg * 256 + (colg - 256))
                                : (v8 + (size_t)rowg * 256 + (colg - 512));
      *(int2*)dst = pk;
    }
  }
}

// Fused MLP: xout = resid + gelu(act @ W1 + b1) @ W2 + b2, all bf16 math.
// Block = 64 rows, 4 waves; wave w owns rows [w*16, w*16+16) exclusively.
// act staged in LDS (XOR-swizzled); a1 chunk round-trips a wave-private LDS
// slice (no inner barriers); W1/W2 fragments read directly from global (L2).
// w1T [1024][256] bf16 (row = fc1 out), w2T [256][1024] bf16 (row = fc2 out).
__global__ __launch_bounds__(256) void mlp_k(
    const short* __restrict__ act, const short* __restrict__ w1T,
    const float* __restrict__ b1, const short* __restrict__ w2T,
    const float* __restrict__ b2, const float* __restrict__ resid,
    float* __restrict__ xout) {
  __shared__ __align__(16) short lact[64 * 256];   // 32 KB
  __shared__ __align__(16) short la1[4][16 * 128]; // 16 KB, per-wave slices
  const int tid = threadIdx.x;
  const int l = tid & 63, w = tid >> 6;
  const int nwg = gridDim.x;  // 1024
  const int bid = blockIdx.x;
  const int swz = (bid & 7) * (nwg >> 3) + (bid >> 3);
  const int m0 = swz << 6;

  // stage act[64][256]: inverse-swizzled source, linear LDS dest
  {
    const int sr = w * 2 + (l >> 5);                 // 0..7
    const int sc = ((l & 31) << 3) ^ ((sr & 7) << 3);
    const short* gA = act + (size_t)(m0 + sr) * 256 + sc;
#pragma unroll
    for (int it = 0; it < 8; ++it)
      gload16(gA + (size_t)(it * 8) * 256, &lact[(it * 8 + w * 2) * 256]);
  }
  __syncthreads();

  f32x4 acc2[16];
#pragma unroll
  for (int i = 0; i < 16; ++i) acc2[i] = f32x4{0.f, 0.f, 0.f, 0.f};

  const int arow = w * 16 + (l & 15);   // this lane's A row in lact
  const int rxor = (l & 7) << 3;        // (arow & 7) << 3  (w*16 % 8 == 0)
  const int lrr = ((l >> 4) << 2);      // D-row base within 16-row group

  for (int nc = 0; nc < 8; ++nc) {
    // ---- fc1 chunk: a1c[16 rows][128 cols] per wave ----
    f32x4 acc1[8];
#pragma unroll
    for (int i = 0; i < 8; ++i) acc1[i] = f32x4{0.f, 0.f, 0.f, 0.f};
#pragma unroll
    for (int kc = 0; kc < 8; ++kc) {
      int ce = (kc * 32 + ((l >> 4) << 3)) ^ rxor;
      bf16x8 aF = *(const bf16x8*)(lact + arow * 256 + ce);
      int wcol = kc * 32 + ((l >> 4) << 3);
#pragma unroll
      for (int nf = 0; nf < 8; ++nf) {
        int wrow = nc * 128 + nf * 16 + (l & 15);
        bf16x8 bF = *(const bf16x8*)(w1T + (size_t)wrow * 256 + wcol);
        acc1[nf] = __builtin_amdgcn_mfma_f32_16x16x32_bf16(aF, bF, acc1[nf], 0, 0, 0);
      }
    }
    // ---- gelu -> wave-private la1[16][128] (XOR-swizzled) ----
#pragma unroll
    for (int nf = 0; nf < 8; ++nf) {
#pragma unroll
      for (int j = 0; j < 4; ++j) {
        int colc = nf * 16 + (l & 15);
        float v = gelu_fast(acc1[nf][j] + b1[nc * 128 + colc]);
        int rr = lrr + j;
        la1[w][rr * 128 + (colc ^ ((rr & 7) << 3))] = (short)f2bf(v);
      }
    }
    // ---- fc2 chunk: acc2 += a1c @ W2[nc*128..+128, :] ----
#pragma unroll
    for (int kc = 0; kc < 4; ++kc) {
      int rr = l & 15;
      int ce = (kc * 32 + ((l >> 4) << 3)) ^ ((rr & 7) << 3);
      bf16x8 aF = *(const bf16x8*)(&la1[w][rr * 128 + ce]);
      int kcol = nc * 128 + kc * 32 + ((l >> 4) << 3);
#pragma unroll
      for (int nf = 0; nf < 16; ++nf) {
        int orow = nf * 16 + (l & 15);
        bf16x8 bF = *(const bf16x8*)(w2T + (size_t)orow * 1024 + kcol);
        acc2[nf] = __builtin_amdgcn_mfma_f32_16x16x32_bf16(aF, bF, acc2[nf], 0, 0, 0);
      }
    }
  }

  // epilogue: + b2 + resid -> f32
#pragma unroll
  for (int nf = 0; nf < 16; ++nf) {
#pragma unroll
    for (int j = 0; j < 4; ++j) {
      int row = m0 + w * 16 + lrr + j;
      int col = nf * 16 + (l & 15);
      float v = acc2[nf][j] + b2[col] + resid[(size_t)row * 256 + col];
      xout[(size_t)row * 256 + col] = v;
    }
  }
}

extern "C" void kernel_launch(void* const* d_in, const int* in_sizes, int n_in,
                              void* d_out, int out_size, void* d_ws, size_t ws_size,
                              hipStream_t stream) {
  const float* in_x   = (const float*)d_in[0];
  const int*   knn    = (const int*)d_in[1];
  const float* ln1_g  = (const float*)d_in[2];
  const float* ln1_b  = (const float*)d_in[3];
  const float* w_qkv  = (const float*)d_in[4];
  const float* w_proj = (const float*)d_in[5];
  const float* b_proj = (const float*)d_in[6];
  const float* ln2_g  = (const float*)d_in[7];
  const float* ln2_b  = (const float*)d_in[8];
  const float* w_fc1  = (const float*)d_in[9];
  const float* b_fc1  = (const float*)d_in[10];
  const float* w_fc2  = (const float*)d_in[11];
  const float* b_fc2  = (const float*)d_in[12];

  // Workspace layout (max ~167 MB):
  //   x    [0,   64) MB   f32 [N][256]
  //   act  [64,  96) MB   bf16 [N][256] (LN out; attn out overwrites it)
  //   q_bf [96, 128) MB   bf16 [N][256]
  //   k8   [128,144) MB   fp8 [N][256]
  //   v8   [144,160) MB   fp8 [N][256]
  //   wT   [160,166.3) MB  transposed bf16 weights
  char* ws = (char*)d_ws;
  float* x    = (float*)(ws);
  short* act  = (short*)(ws + 67108864);
  short* q_bf = (short*)(ws + 100663296);
  uchar* k8   = (uchar*)(ws + 134217728);
  uchar* v8   = (uchar*)(ws + 150994944);
  short* wT   = (short*)(ws + 167772160);
  short* wqkvT  = wT;                // [L][768][256]
  short* wprojT = wT + 786432;       // [L][256][256]
  short* wfc1T  = wT + 1048576;      // [L][1024][256]
  short* wfc2T  = wT + 2097152;      // [L][256][1024]

  wcast<<<dim3(768, 4), 256, 0, stream>>>(w_qkv, wqkvT, 256, 768);
  wcast<<<dim3(256, 4), 256, 0, stream>>>(w_proj, wprojT, 256, 256);
  wcast<<<dim3(1024, 4), 256, 0, stream>>>(w_fc1, wfc1T, 256, 1024);
  wcast<<<dim3(1024, 4), 256, 0, stream>>>(w_fc2, wfc2T, 1024, 256);

  for (int i = 0; i < 4; ++i) {
    const float* xin = (i == 0) ? in_x : x;
    ln_k<<<16384, 256, 0, stream>>>(xin, ln1_g + i * 256, ln1_b + i * 256, act);
    gemm_k<3, 256><<<3072, 256, 0, stream>>>(
        act, wqkvT + (size_t)i * 196608, nullptr, nullptr, q_bf, nullptr,
        k8, v8, 768, 6);
    attn_k<<<16384, 256, 0, stream>>>(q_bf, k8, v8, knn, act);
    gemm_k<1, 256><<<1024, 256, 0, stream>>>(
        act, wprojT + (size_t)i * 65536, b_proj + i * 256, xin, nullptr, x,
        nullptr, nullptr, 256, 2);
    ln_k<<<16384, 256, 0, stream>>>(x, ln2_g + i * 256, ln2_b + i * 256, act);
    mlp_k<<<1024, 256, 0, stream>>>(
        act, wfc1T + (size_t)i * 262144, b_fc1 + i * 1024,
        wfc2T + (size_t)i * 262144, b_fc2 + i * 256, x,
        (i == 3) ? (float*)d_out : x);
  }
}

// Round 14
// 1283.047 us; speedup vs baseline: 2.8304x; 2.8304x over previous
//
#include <hip/hip_runtime.h>

typedef __attribute__((ext_vector_type(4))) float  f32x4;
typedef __attribute__((ext_vector_type(2))) float  f32x2;
typedef __attribute__((ext_vector_type(8))) __bf16 bf16x8;
typedef __attribute__((ext_vector_type(4))) short  s16x4;
typedef __attribute__((ext_vector_type(8))) short  s16x8;
typedef unsigned char uchar;

__device__ __forceinline__ unsigned short f2bf(float f) {
  unsigned u = __builtin_bit_cast(unsigned, f);
  u += 0x7FFFu + ((u >> 16) & 1u);
  return (unsigned short)(u >> 16);
}
__device__ __forceinline__ float b2f(short s) {
  return __builtin_bit_cast(float, (unsigned)((unsigned short)s) << 16);
}
__device__ __forceinline__ uchar f2fp8(float v) {
  return (uchar)(__builtin_amdgcn_cvt_pk_fp8_f32(v, v, 0, false) & 0xFF);
}
__device__ __forceinline__ float gelu_fast(float v) {
  float u = v * (0.7978845608f + 0.0356774081f * v * v);
  float t = __expf(-2.f * fabsf(u));
  float th = (1.f - t) / (1.f + t);
  th = (u >= 0.f) ? th : -th;
  return 0.5f * v * (1.f + th);
}

__device__ __forceinline__ void gload16(const void* g, void* l) {
  __builtin_amdgcn_global_load_lds(
      (const __attribute__((address_space(1))) void*)g,
      (__attribute__((address_space(3))) void*)l, 16, 0, 0);
}

// Transpose + cast weights: W [L][In][Out] f32 -> WT [L][Out][In] bf16
__global__ __launch_bounds__(256) void wcast(const float* __restrict__ W,
                                             short* __restrict__ WT,
                                             int In, int Out) {
  int i = blockIdx.x * 256 + threadIdx.x;
  int lay = blockIdx.y;
  if (i >= In * Out) return;
  const float* w = W + (size_t)lay * In * Out;
  short* wt = WT + (size_t)lay * In * Out;
  int ii = i % In, oo = i / In;
  wt[(size_t)oo * In + ii] = (short)f2bf(w[(size_t)ii * Out + oo]);
}

// w_fc2 [L][1024][256] f32 -> fp8 [L][256][1024], scaled x64
__global__ __launch_bounds__(256) void wcast8(const float* __restrict__ W,
                                              uchar* __restrict__ WT8) {
  int i = blockIdx.x * 256 + threadIdx.x;  // over 1024*256
  int lay = blockIdx.y;
  const float* w = W + (size_t)lay * 262144;
  uchar* wt = WT8 + (size_t)lay * 262144;
  int ii = i % 1024, oo = i / 1024;  // ii = K index, oo = out col
  wt[(size_t)oo * 1024 + ii] = f2fp8(64.f * w[(size_t)ii * 256 + oo]);
}

// LayerNorm over C=256, one wave per row, write bf16
__global__ __launch_bounds__(256) void ln_k(const float* __restrict__ x,
                                            const float* __restrict__ g,
                                            const float* __restrict__ b,
                                            short* __restrict__ out) {
  int row = blockIdx.x * 4 + (threadIdx.x >> 6);
  int l = threadIdx.x & 63;
  const float4 v = *(const float4*)(x + (size_t)row * 256 + l * 4);
  float s  = v.x + v.y + v.z + v.w;
  float ss = v.x * v.x + v.y * v.y + v.z * v.z + v.w * v.w;
#pragma unroll
  for (int o = 32; o >= 1; o >>= 1) {
    s  += __shfl_xor(s, o);
    ss += __shfl_xor(ss, o);
  }
  float mean = s * (1.0f / 256.0f);
  float var  = ss * (1.0f / 256.0f) - mean * mean;
  float rstd = rsqrtf(var + 1e-5f);
  const float4 gg = *(const float4*)(g + l * 4);
  const float4 bb = *(const float4*)(b + l * 4);
  s16x4 o4;
  o4[0] = (short)f2bf((v.x - mean) * rstd * gg.x + bb.x);
  o4[1] = (short)f2bf((v.y - mean) * rstd * gg.y + bb.y);
  o4[2] = (short)f2bf((v.z - mean) * rstd * gg.z + bb.z);
  o4[3] = (short)f2bf((v.w - mean) * rstd * gg.w + bb.w);
  *(s16x4*)(out + (size_t)row * 256 + l * 4) = o4;
}

// KNN attention: one wave per point. q bf16 [N][256], k8/v8 fp8 [N][256]
__global__ __launch_bounds__(256) void attn_k(const short* __restrict__ q_,
                                              const uchar* __restrict__ k8,
                                              const uchar* __restrict__ v8,
                                              const int* __restrict__ knn,
                                              short* __restrict__ out) {
  int n = blockIdx.x * 4 + (threadIdx.x >> 6);
  int l = threadIdx.x & 63;
  int j = l & 15, g = l >> 4;
  int idxj = knn[(size_t)n * 16 + j];
  const short* qp = q_ + (size_t)n * 256 + g * 64;
  const uchar* kp = k8 + (size_t)idxj * 256 + g * 64;
  float partial = 0.f;
#pragma unroll
  for (int t = 0; t < 4; ++t) {  // 16 channels per t
    int4 kv = *(const int4*)(kp + t * 16);
    s16x8 q0 = *(const s16x8*)(qp + t * 16);
    s16x8 q1 = *(const s16x8*)(qp + t * 16 + 8);
    f32x2 a;
    a = __builtin_amdgcn_cvt_pk_f32_fp8(kv.x, false);
    partial += a[0] * b2f(q0[0]) + a[1] * b2f(q0[1]);
    a = __builtin_amdgcn_cvt_pk_f32_fp8(kv.x, true);
    partial += a[0] * b2f(q0[2]) + a[1] * b2f(q0[3]);
    a = __builtin_amdgcn_cvt_pk_f32_fp8(kv.y, false);
    partial += a[0] * b2f(q0[4]) + a[1] * b2f(q0[5]);
    a = __builtin_amdgcn_cvt_pk_f32_fp8(kv.y, true);
    partial += a[0] * b2f(q0[6]) + a[1] * b2f(q0[7]);
    a = __builtin_amdgcn_cvt_pk_f32_fp8(kv.z, false);
    partial += a[0] * b2f(q1[0]) + a[1] * b2f(q1[1]);
    a = __builtin_amdgcn_cvt_pk_f32_fp8(kv.z, true);
    partial += a[0] * b2f(q1[2]) + a[1] * b2f(q1[3]);
    a = __builtin_amdgcn_cvt_pk_f32_fp8(kv.w, false);
    partial += a[0] * b2f(q1[4]) + a[1] * b2f(q1[5]);
    a = __builtin_amdgcn_cvt_pk_f32_fp8(kv.w, true);
    partial += a[0] * b2f(q1[6]) + a[1] * b2f(q1[7]);
  }
  partial += __shfl_xor(partial, 16);
  partial += __shfl_xor(partial, 32);
  float score = partial * 0.0625f;  // C^-0.5, C=256
  float mx = score;
#pragma unroll
  for (int o = 1; o < 16; o <<= 1) mx = fmaxf(mx, __shfl_xor(mx, o));
  float e = __expf(score - mx);
  float sum = e;
#pragma unroll
  for (int o = 1; o < 16; o <<= 1) sum += __shfl_xor(sum, o);
  float attn = e / sum;
  float4 o4 = {0.f, 0.f, 0.f, 0.f};
#pragma unroll
  for (int jj = 0; jj < 16; ++jj) {
    float aj = __shfl(attn, jj);
    int   ij = __shfl(idxj, jj);
    int vv = *(const int*)(v8 + (size_t)ij * 256 + l * 4);
    f32x2 lo = __builtin_amdgcn_cvt_pk_f32_fp8(vv, false);
    f32x2 hi = __builtin_amdgcn_cvt_pk_f32_fp8(vv, true);
    o4.x += aj * lo[0];
    o4.y += aj * lo[1];
    o4.z += aj * hi[0];
    o4.w += aj * hi[1];
  }
  s16x4 ob;
  ob[0] = (short)f2bf(o4.x);
  ob[1] = (short)f2bf(o4.y);
  ob[2] = (short)f2bf(o4.z);
  ob[3] = (short)f2bf(o4.w);
  *(s16x4*)(out + (size_t)n * 256 + l * 4) = ob;
}

// GEMM: A [M][KD] bf16 x BT [Nout][KD] bf16 -> out [M][Nout]
// v3: explicit LDS double-buffer + counted vmcnt (T3/T4 minimum recipe).
// Stage tile kt+1 BEFORE computing tile kt; s_waitcnt vmcnt(8) (next tile's 8
// loads stay in flight) + raw s_barrier; compute; s_barrier (buffer reuse).
// EPI 1: +bias +resid(f32) -> f32.  EPI 2: +bias, gelu -> fp8 x16 (packed).
// EPI 3: qkv split -> q bf16 / k8 fp8 / v8 fp8 (LDS-transpose epilogue).
// 128x128 tile, BK=64, 4 waves (2x2), T2 XOR swizzle, T1 XCD-chunked swizzle.
template <int EPI, int KD>
__global__ __launch_bounds__(256) void gemm_k(
    const short* __restrict__ A, const short* __restrict__ BT,
    const float* __restrict__ bias, const float* __restrict__ resid,
    short* __restrict__ outb, float* __restrict__ outf,
    uchar* __restrict__ k8, uchar* __restrict__ v8, int Nout, int gx) {
  // pool: 2 x (16K A + 16K B) double-buffer; epilogue reuses first 36K.
  __shared__ __align__(16) char pool[65536];
  const int tid = threadIdx.x;
  const int l = tid & 63, w = tid >> 6;
  const int nwg = gridDim.x;
  const int bid = blockIdx.x;
  const int swz = (bid & 7) * (nwg >> 3) + (bid >> 3);
  const int m0 = (swz / gx) << 7, n0 = (swz % gx) << 7;
  const int wm = w >> 1, wn = w & 1;

  f32x4 acc[4][4];
#pragma unroll
  for (int i = 0; i < 4; ++i)
#pragma unroll
    for (int jj = 0; jj < 4; ++jj) acc[i][jj] = f32x4{0.f, 0.f, 0.f, 0.f};

  const int srow = (w << 3) + (l >> 3);
  const int scol = (((l & 7) << 3)) ^ ((srow & 7) << 3);
  const short* gA = A + (size_t)(m0 + srow) * KD + scol;
  const short* gB = BT + (size_t)(n0 + srow) * KD + scol;

  auto stage = [&](int kt, int b) {
    short* sA = (short*)(pool + b * 32768);
    short* sB = (short*)(pool + b * 32768 + 16384);
#pragma unroll
    for (int it = 0; it < 4; ++it) {
      gload16(gA + (size_t)(it * 32) * KD + kt, &sA[(it * 32 + w * 8) * 64]);
      gload16(gB + (size_t)(it * 32) * KD + kt, &sB[(it * 32 + w * 8) * 64]);
    }
  };

  stage(0, 0);
#pragma unroll
  for (int kt = 0; kt < KD; kt += 64) {
    const int b = (kt >> 6) & 1;
    if (kt + 64 < KD) {
      stage(kt + 64, b ^ 1);
      asm volatile("s_waitcnt vmcnt(8)" ::: "memory");
    } else {
      asm volatile("s_waitcnt vmcnt(0)" ::: "memory");
    }
    __builtin_amdgcn_sched_barrier(0);
    __builtin_amdgcn_s_barrier();
    const short* lA = (const short*)(pool + b * 32768);
    const short* lB = (const short*)(pool + b * 32768 + 16384);
#pragma unroll
    for (int kc = 0; kc < 2; ++kc) {
      bf16x8 aF[4], bF[4];
#pragma unroll
      for (int f = 0; f < 4; ++f) {
        int r = wm * 64 + f * 16 + (l & 15);
        int ce = (kc * 32 + ((l >> 4) << 3)) ^ ((r & 7) << 3);
        aF[f] = *(const bf16x8*)(lA + r * 64 + ce);
      }
#pragma unroll
      for (int f = 0; f < 4; ++f) {
        int r = wn * 64 + f * 16 + (l & 15);
        int ce = (kc * 32 + ((l >> 4) << 3)) ^ ((r & 7) << 3);
        bF[f] = *(const bf16x8*)(lB + r * 64 + ce);
      }
#pragma unroll
      for (int mf = 0; mf < 4; ++mf)
#pragma unroll
        for (int nf = 0; nf < 4; ++nf)
          acc[mf][nf] = __builtin_amdgcn_mfma_f32_16x16x32_bf16(
              aF[mf], bF[nf], acc[mf][nf], 0, 0, 0);
    }
    __builtin_amdgcn_s_barrier();
  }

  const int lr = (l >> 4) << 2, lc = l & 15;
  if (EPI == 1) {
#pragma unroll
    for (int mf = 0; mf < 4; ++mf) {
#pragma unroll
      for (int nf = 0; nf < 4; ++nf) {
#pragma unroll
        for (int jj = 0; jj < 4; ++jj) {
          int row = m0 + wm * 64 + mf * 16 + lr + jj;
          int col = n0 + wn * 64 + nf * 16 + lc;
          float v = acc[mf][nf][jj] + bias[col] + resid[(size_t)row * 256 + col];
          outf[(size_t)row * 256 + col] = v;
        }
      }
    }
    return;
  }

  // EPI 2/3: wave-private LDS transpose -> coalesced packed stores.
  short* myL = (short*)(pool + w * 9216);
#pragma unroll
  for (int mf = 0; mf < 4; ++mf) {
#pragma unroll
    for (int nf = 0; nf < 4; ++nf) {
#pragma unroll
      for (int jj = 0; jj < 4; ++jj) {
        int rl = mf * 16 + lr + jj;
        int cl = nf * 16 + lc;
        float v = acc[mf][nf][jj];
        if (EPI == 2) v = gelu_fast(v + bias[n0 + wn * 64 + cl]);
        myL[rl * 72 + cl] = (short)f2bf(v);
      }
    }
  }
#pragma unroll
  for (int it = 0; it < 8; ++it) {
    int rl = it * 8 + (l >> 3);
    int cl = (l & 7) * 8;
    s16x8 vv = *(const s16x8*)(myL + rl * 72 + cl);
    int rowg = m0 + wm * 64 + rl;
    int colg = n0 + wn * 64 + cl;
    if (EPI == 2) {
      unsigned w0 = __builtin_amdgcn_cvt_pk_fp8_f32(16.f * b2f(vv[0]), 16.f * b2f(vv[1]), 0, false);
      w0 = __builtin_amdgcn_cvt_pk_fp8_f32(16.f * b2f(vv[2]), 16.f * b2f(vv[3]), w0, true);
      unsigned w1 = __builtin_amdgcn_cvt_pk_fp8_f32(16.f * b2f(vv[4]), 16.f * b2f(vv[5]), 0, false);
      w1 = __builtin_amdgcn_cvt_pk_fp8_f32(16.f * b2f(vv[6]), 16.f * b2f(vv[7]), w1, true);
      *(int2*)(k8 + (size_t)rowg * Nout + colg) = make_int2((int)w0, (int)w1);
    } else {  // EPI 3: qkv split
      if (colg < 256) {
        *(s16x8*)(outb + (size_t)rowg * 256 + colg) = vv;
      } else {
        unsigned w0 = __builtin_amdgcn_cvt_pk_fp8_f32(b2f(vv[0]), b2f(vv[1]), 0, false);
        w0 = __builtin_amdgcn_cvt_pk_fp8_f32(b2f(vv[2]), b2f(vv[3]), w0, true);
        unsigned w1 = __builtin_amdgcn_cvt_pk_fp8_f32(b2f(vv[4]), b2f(vv[5]), 0, false);
        w1 = __builtin_amdgcn_cvt_pk_fp8_f32(b2f(vv[6]), b2f(vv[7]), w1, true);
        int2 pk = make_int2((int)w0, (int)w1);
        uchar* dst = (colg < 512) ? (k8 + (size_t)rowg * 256 + (colg - 256))
                                  : (v8 + (size_t)rowg * 256 + (colg - 512));
        *(int2*)dst = pk;
      }
    }
  }
}

// fc2: A8 fp8 [M][1024] (a1 x16) x B8 fp8 [256][1024] (w x64) -> f32
// out = acc/1024 + bias + resid. 128x128 tile, BK=64, fp8 MFMA.
__global__ __launch_bounds__(256) void gemm_fp8(
    const uchar* __restrict__ A8, const uchar* __restrict__ B8,
    const float* __restrict__ bias, const float* __restrict__ resid,
    float* __restrict__ outf) {
  __shared__ __align__(16) uchar lA8[8192];
  __shared__ __align__(16) uchar lB8[8192];
  const int tid = threadIdx.x;
  const int l = tid & 63, w = tid >> 6;
  const int nwg = gridDim.x;
  const int bid = blockIdx.x;
  const int swz = (bid & 7) * (nwg >> 3) + (bid >> 3);
  const int m0 = (swz >> 1) << 7, n0 = (swz & 1) << 7;
  const int wm = w >> 1, wn = w & 1;

  f32x4 acc[4][4];
#pragma unroll
  for (int i = 0; i < 4; ++i)
#pragma unroll
    for (int jj = 0; jj < 4; ++jj) acc[i][jj] = f32x4{0.f, 0.f, 0.f, 0.f};

  const int sr = (w << 4) + (l >> 2);
  const int sc = ((l & 3) << 4) ^ ((sr & 3) << 4);
  const uchar* gA = A8 + (size_t)(m0 + sr) * 1024 + sc;
  const uchar* gB = B8 + (size_t)(n0 + sr) * 1024 + sc;

  for (int kt = 0; kt < 1024; kt += 64) {
#pragma unroll
    for (int it = 0; it < 2; ++it) {
      gload16(gA + (size_t)(it * 64) * 1024 + kt, &lA8[(it * 64 + w * 16) * 64]);
      gload16(gB + (size_t)(it * 64) * 1024 + kt, &lB8[(it * 64 + w * 16) * 64]);
    }
    __syncthreads();
#pragma unroll
    for (int kc = 0; kc < 2; ++kc) {
      long aF[4], bF[4];
#pragma unroll
      for (int f = 0; f < 4; ++f) {
        int r = wm * 64 + f * 16 + (l & 15);
        int cs = (kc * 32 + ((l >> 4) << 3)) ^ ((r & 3) << 4);
        aF[f] = *(const long*)(lA8 + r * 64 + cs);
      }
#pragma unroll
      for (int f = 0; f < 4; ++f) {
        int r = wn * 64 + f * 16 + (l & 15);
        int cs = (kc * 32 + ((l >> 4) << 3)) ^ ((r & 3) << 4);
        bF[f] = *(const long*)(lB8 + r * 64 + cs);
      }
#pragma unroll
      for (int mf = 0; mf < 4; ++mf)
#pragma unroll
        for (int nf = 0; nf < 4; ++nf)
          acc[mf][nf] = __builtin_amdgcn_mfma_f32_16x16x32_fp8_fp8(
              aF[mf], bF[nf], acc[mf][nf], 0, 0, 0);
    }
    __syncthreads();
  }

  const int lr = (l >> 4) << 2, lc = l & 15;
#pragma unroll
  for (int mf = 0; mf < 4; ++mf) {
#pragma unroll
    for (int nf = 0; nf < 4; ++nf) {
#pragma unroll
      for (int jj = 0; jj < 4; ++jj) {
        int row = m0 + wm * 64 + mf * 16 + lr + jj;
        int col = n0 + wn * 64 + nf * 16 + lc;
        float v = acc[mf][nf][jj] * (1.0f / 1024.0f) + bias[col] +
                  resid[(size_t)row * 256 + col];
        outf[(size_t)row * 256 + col] = v;
      }
    }
  }
}

extern "C" void kernel_launch(void* const* d_in, const int* in_sizes, int n_in,
                              void* d_out, int out_size, void* d_ws, size_t ws_size,
                              hipStream_t stream) {
  const float* in_x   = (const float*)d_in[0];
  const int*   knn    = (const int*)d_in[1];
  const float* ln1_g  = (const float*)d_in[2];
  const float* ln1_b  = (const float*)d_in[3];
  const float* w_qkv  = (const float*)d_in[4];
  const float* w_proj = (const float*)d_in[5];
  const float* b_proj = (const float*)d_in[6];
  const float* ln2_g  = (const float*)d_in[7];
  const float* ln2_b  = (const float*)d_in[8];
  const float* w_fc1  = (const float*)d_in[9];
  const float* b_fc1  = (const float*)d_in[10];
  const float* w_fc2  = (const float*)d_in[11];
  const float* b_fc2  = (const float*)d_in[12];

  // Workspace layout (max 230.3 MB) — identical to R10:
  char* ws = (char*)d_ws;
  float* x    = (float*)(ws);
  short* act  = (short*)(ws + 67108864);
  uchar* big8 = (uchar*)(ws + 100663296);
  short* q_bf = (short*)(ws + 167772160);
  uchar* k8   = (uchar*)(ws + 201326592);
  uchar* v8   = (uchar*)(ws + 218103808);
  short* wT   = (short*)(ws + 234881024);
  short* wqkvT  = wT;                        // [L][768][256] bf16
  short* wprojT = wT + 786432;               // [L][256][256] bf16
  short* wfc1T  = wT + 1048576;              // [L][1024][256] bf16
  uchar* wfc2T8 = (uchar*)(wT + 2097152);    // [L][256][1024] fp8 (x64)

  wcast<<<dim3(768, 4), 256, 0, stream>>>(w_qkv, wqkvT, 256, 768);
  wcast<<<dim3(256, 4), 256, 0, stream>>>(w_proj, wprojT, 256, 256);
  wcast<<<dim3(1024, 4), 256, 0, stream>>>(w_fc1, wfc1T, 256, 1024);
  wcast8<<<dim3(1024, 4), 256, 0, stream>>>(w_fc2, wfc2T8);

  for (int i = 0; i < 4; ++i) {
    const float* xin = (i == 0) ? in_x : x;
    ln_k<<<16384, 256, 0, stream>>>(xin, ln1_g + i * 256, ln1_b + i * 256, act);
    gemm_k<3, 256><<<3072, 256, 0, stream>>>(
        act, wqkvT + (size_t)i * 196608, nullptr, nullptr, q_bf, nullptr,
        k8, v8, 768, 6);
    attn_k<<<16384, 256, 0, stream>>>(q_bf, k8, v8, knn, act);
    gemm_k<1, 256><<<1024, 256, 0, stream>>>(
        act, wprojT + (size_t)i * 65536, b_proj + i * 256, xin, nullptr, x,
        nullptr, nullptr, 256, 2);
    ln_k<<<16384, 256, 0, stream>>>(x, ln2_g + i * 256, ln2_b + i * 256, act);
    gemm_k<2, 256><<<4096, 256, 0, stream>>>(
        act, wfc1T + (size_t)i * 262144, b_fc1 + i * 1024, nullptr, nullptr,
        nullptr, big8, nullptr, 1024, 8);
    gemm_fp8<<<1024, 256, 0, stream>>>(
        big8, wfc2T8 + (size_t)i * 262144, b_fc2 + i * 256, x,
        (i == 3) ? (float*)d_out : x);
  }
}

// Round 15
// 1083.933 us; speedup vs baseline: 3.3503x; 1.1837x over previous
//
#include <hip/hip_runtime.h>

typedef __attribute__((ext_vector_type(4))) float  f32x4;
typedef __attribute__((ext_vector_type(2))) float  f32x2;
typedef __attribute__((ext_vector_type(8))) __bf16 bf16x8;
typedef __attribute__((ext_vector_type(4))) short  s16x4;
typedef __attribute__((ext_vector_type(8))) short  s16x8;
typedef unsigned char uchar;

__device__ __forceinline__ unsigned short f2bf(float f) {
  unsigned u = __builtin_bit_cast(unsigned, f);
  u += 0x7FFFu + ((u >> 16) & 1u);
  return (unsigned short)(u >> 16);
}
__device__ __forceinline__ float b2f(short s) {
  return __builtin_bit_cast(float, (unsigned)((unsigned short)s) << 16);
}
// sigmoid-form gelu: ~4 VALU ops (vs ~12 for tanh-form)
__device__ __forceinline__ float gelu_sig(float v) {
  float t = __expf(-1.702f * v);
  return v * __builtin_amdgcn_rcpf(1.f + t);
}

__device__ __forceinline__ void gload16(const void* g, void* l) {
  __builtin_amdgcn_global_load_lds(
      (const __attribute__((address_space(1))) void*)g,
      (__attribute__((address_space(3))) void*)l, 16, 0, 0);
}

// in_x f32 -> xb bf16 (once)
__global__ __launch_bounds__(256) void x2bf(const float* __restrict__ x,
                                            short* __restrict__ xb) {
  int i = blockIdx.x * 256 + threadIdx.x;
  float4 v = *(const float4*)(x + (size_t)i * 4);
  s16x4 o;
  o[0] = (short)f2bf(v.x);
  o[1] = (short)f2bf(v.y);
  o[2] = (short)f2bf(v.z);
  o[3] = (short)f2bf(v.w);
  *(s16x4*)(xb + (size_t)i * 4) = o;
}

// Transpose + cast weights: W [L][In][Out] f32 -> WT [L][Out][In] bf16
__global__ __launch_bounds__(256) void wcast(const float* __restrict__ W,
                                             short* __restrict__ WT,
                                             int In, int Out) {
  int i = blockIdx.x * 256 + threadIdx.x;
  int lay = blockIdx.y;
  if (i >= In * Out) return;
  const float* w = W + (size_t)lay * In * Out;
  short* wt = WT + (size_t)lay * In * Out;
  int ii = i % In, oo = i / In;
  wt[(size_t)oo * In + ii] = (short)f2bf(w[(size_t)ii * Out + oo]);
}

// LayerNorm over C=256, bf16 in -> bf16 out, one wave per row
__global__ __launch_bounds__(256) void ln_k(const short* __restrict__ xb,
                                            const float* __restrict__ g,
                                            const float* __restrict__ b,
                                            short* __restrict__ out) {
  int row = blockIdx.x * 4 + (threadIdx.x >> 6);
  int l = threadIdx.x & 63;
  const s16x4 vb = *(const s16x4*)(xb + (size_t)row * 256 + l * 4);
  float v0 = b2f(vb[0]), v1 = b2f(vb[1]), v2 = b2f(vb[2]), v3 = b2f(vb[3]);
  float s  = v0 + v1 + v2 + v3;
  float ss = v0 * v0 + v1 * v1 + v2 * v2 + v3 * v3;
#pragma unroll
  for (int o = 32; o >= 1; o >>= 1) {
    s  += __shfl_xor(s, o);
    ss += __shfl_xor(ss, o);
  }
  float mean = s * (1.0f / 256.0f);
  float var  = ss * (1.0f / 256.0f) - mean * mean;
  float rstd = rsqrtf(var + 1e-5f);
  const float4 gg = *(const float4*)(g + l * 4);
  const float4 bb = *(const float4*)(b + l * 4);
  s16x4 o4;
  o4[0] = (short)f2bf((v0 - mean) * rstd * gg.x + bb.x);
  o4[1] = (short)f2bf((v1 - mean) * rstd * gg.y + bb.y);
  o4[2] = (short)f2bf((v2 - mean) * rstd * gg.z + bb.z);
  o4[3] = (short)f2bf((v3 - mean) * rstd * gg.w + bb.w);
  *(s16x4*)(out + (size_t)row * 256 + l * 4) = o4;
}

// KNN attention: one wave per point. q bf16 [N][256], k8/v8 fp8 [N][256]
__global__ __launch_bounds__(256) void attn_k(const short* __restrict__ q_,
                                              const uchar* __restrict__ k8,
                                              const uchar* __restrict__ v8,
                                              const int* __restrict__ knn,
                                              short* __restrict__ out) {
  int n = blockIdx.x * 4 + (threadIdx.x >> 6);
  int l = threadIdx.x & 63;
  int j = l & 15, g = l >> 4;
  int idxj = knn[(size_t)n * 16 + j];
  const short* qp = q_ + (size_t)n * 256 + g * 64;
  const uchar* kp = k8 + (size_t)idxj * 256 + g * 64;
  float partial = 0.f;
#pragma unroll
  for (int t = 0; t < 4; ++t) {  // 16 channels per t
    int4 kv = *(const int4*)(kp + t * 16);
    s16x8 q0 = *(const s16x8*)(qp + t * 16);
    s16x8 q1 = *(const s16x8*)(qp + t * 16 + 8);
    f32x2 a;
    a = __builtin_amdgcn_cvt_pk_f32_fp8(kv.x, false);
    partial += a[0] * b2f(q0[0]) + a[1] * b2f(q0[1]);
    a = __builtin_amdgcn_cvt_pk_f32_fp8(kv.x, true);
    partial += a[0] * b2f(q0[2]) + a[1] * b2f(q0[3]);
    a = __builtin_amdgcn_cvt_pk_f32_fp8(kv.y, false);
    partial += a[0] * b2f(q0[4]) + a[1] * b2f(q0[5]);
    a = __builtin_amdgcn_cvt_pk_f32_fp8(kv.y, true);
    partial += a[0] * b2f(q0[6]) + a[1] * b2f(q0[7]);
    a = __builtin_amdgcn_cvt_pk_f32_fp8(kv.z, false);
    partial += a[0] * b2f(q1[0]) + a[1] * b2f(q1[1]);
    a = __builtin_amdgcn_cvt_pk_f32_fp8(kv.z, true);
    partial += a[0] * b2f(q1[2]) + a[1] * b2f(q1[3]);
    a = __builtin_amdgcn_cvt_pk_f32_fp8(kv.w, false);
    partial += a[0] * b2f(q1[4]) + a[1] * b2f(q1[5]);
    a = __builtin_amdgcn_cvt_pk_f32_fp8(kv.w, true);
    partial += a[0] * b2f(q1[6]) + a[1] * b2f(q1[7]);
  }
  partial += __shfl_xor(partial, 16);
  partial += __shfl_xor(partial, 32);
  float score = partial * 0.0625f;  // C^-0.5, C=256
  float mx = score;
#pragma unroll
  for (int o = 1; o < 16; o <<= 1) mx = fmaxf(mx, __shfl_xor(mx, o));
  float e = __expf(score - mx);
  float sum = e;
#pragma unroll
  for (int o = 1; o < 16; o <<= 1) sum += __shfl_xor(sum, o);
  float attn = e / sum;
  float4 o4 = {0.f, 0.f, 0.f, 0.f};
#pragma unroll
  for (int jj = 0; jj < 16; ++jj) {
    float aj = __shfl(attn, jj);
    int   ij = __shfl(idxj, jj);
    int vv = *(const int*)(v8 + (size_t)ij * 256 + l * 4);
    f32x2 lo = __builtin_amdgcn_cvt_pk_f32_fp8(vv, false);
    f32x2 hi = __builtin_amdgcn_cvt_pk_f32_fp8(vv, true);
    o4.x += aj * lo[0];
    o4.y += aj * lo[1];
    o4.z += aj * hi[0];
    o4.w += aj * hi[1];
  }
  s16x4 ob;
  ob[0] = (short)f2bf(o4.x);
  ob[1] = (short)f2bf(o4.y);
  ob[2] = (short)f2bf(o4.z);
  ob[3] = (short)f2bf(o4.w);
  *(s16x4*)(out + (size_t)n * 256 + l * 4) = ob;
}

// GEMM: A [M][KD] bf16 x BT [Nout][KD] bf16 -> out [M][Nout]
// EPI 1: +bias +resid(bf16) -> bf16 xb.  EPI 4: +bias +resid(bf16) -> f32.
// EPI 2: +bias, sigmoid-gelu -> bf16 (LDS-transpose, s16x8 stores).
// EPI 3: qkv split -> q bf16 / k8 fp8 / v8 fp8 (LDS-transpose epilogue).
// 128x128 tile, BK=64, 4 waves (2x2), T2 XOR swizzle, T1 XCD-chunked swizzle.
template <int EPI, int KD>
__global__ __launch_bounds__(256) void gemm_k(
    const short* __restrict__ A, const short* __restrict__ BT,
    const float* __restrict__ bias, const short* __restrict__ residb,
    short* __restrict__ outb, float* __restrict__ outf,
    uchar* __restrict__ k8, uchar* __restrict__ v8, int Nout, int gx) {
  __shared__ __align__(16) char pool[36864];
  short* lA = (short*)pool;
  short* lB = (short*)(pool + 16384);
  const int tid = threadIdx.x;
  const int l = tid & 63, w = tid >> 6;
  const int nwg = gridDim.x;
  const int bid = blockIdx.x;
  const int swz = (bid & 7) * (nwg >> 3) + (bid >> 3);
  const int m0 = (swz / gx) << 7, n0 = (swz % gx) << 7;
  const int wm = w >> 1, wn = w & 1;

  f32x4 acc[4][4];
#pragma unroll
  for (int i = 0; i < 4; ++i)
#pragma unroll
    for (int jj = 0; jj < 4; ++jj) acc[i][jj] = f32x4{0.f, 0.f, 0.f, 0.f};

  const int srow = (w << 3) + (l >> 3);
  const int scol = (((l & 7) << 3)) ^ ((srow & 7) << 3);
  const short* gA = A + (size_t)(m0 + srow) * KD + scol;
  const short* gB = BT + (size_t)(n0 + srow) * KD + scol;

  for (int kt = 0; kt < KD; kt += 64) {
#pragma unroll
    for (int it = 0; it < 4; ++it) {
      gload16(gA + (size_t)(it * 32) * KD + kt, &lA[(it * 32 + w * 8) * 64]);
      gload16(gB + (size_t)(it * 32) * KD + kt, &lB[(it * 32 + w * 8) * 64]);
    }
    __syncthreads();
#pragma unroll
    for (int kc = 0; kc < 2; ++kc) {
      bf16x8 aF[4], bF[4];
#pragma unroll
      for (int f = 0; f < 4; ++f) {
        int r = wm * 64 + f * 16 + (l & 15);
        int ce = (kc * 32 + ((l >> 4) << 3)) ^ ((r & 7) << 3);
        aF[f] = *(const bf16x8*)(lA + r * 64 + ce);
      }
#pragma unroll
      for (int f = 0; f < 4; ++f) {
        int r = wn * 64 + f * 16 + (l & 15);
        int ce = (kc * 32 + ((l >> 4) << 3)) ^ ((r & 7) << 3);
        bF[f] = *(const bf16x8*)(lB + r * 64 + ce);
      }
#pragma unroll
      for (int mf = 0; mf < 4; ++mf)
#pragma unroll
        for (int nf = 0; nf < 4; ++nf)
          acc[mf][nf] = __builtin_amdgcn_mfma_f32_16x16x32_bf16(
              aF[mf], bF[nf], acc[mf][nf], 0, 0, 0);
    }
    __syncthreads();
  }

  const int lr = (l >> 4) << 2, lc = l & 15;
  if (EPI == 1 || EPI == 4) {
#pragma unroll
    for (int mf = 0; mf < 4; ++mf) {
#pragma unroll
      for (int nf = 0; nf < 4; ++nf) {
#pragma unroll
        for (int jj = 0; jj < 4; ++jj) {
          int row = m0 + wm * 64 + mf * 16 + lr + jj;
          int col = n0 + wn * 64 + nf * 16 + lc;
          float v = acc[mf][nf][jj] + bias[col] +
                    b2f(residb[(size_t)row * 256 + col]);
          if (EPI == 1)
            outb[(size_t)row * 256 + col] = (short)f2bf(v);
          else
            outf[(size_t)row * 256 + col] = v;
        }
      }
    }
    return;
  }

  // EPI 2/3: wave-private LDS transpose -> coalesced stores.
  short* myL = (short*)(pool + w * 9216);
#pragma unroll
  for (int mf = 0; mf < 4; ++mf) {
#pragma unroll
    for (int nf = 0; nf < 4; ++nf) {
#pragma unroll
      for (int jj = 0; jj < 4; ++jj) {
        int rl = mf * 16 + lr + jj;
        int cl = nf * 16 + lc;
        float v = acc[mf][nf][jj];
        if (EPI == 2) v = gelu_sig(v + bias[n0 + wn * 64 + cl]);
        myL[rl * 72 + cl] = (short)f2bf(v);
      }
    }
  }
#pragma unroll
  for (int it = 0; it < 8; ++it) {
    int rl = it * 8 + (l >> 3);
    int cl = (l & 7) * 8;
    s16x8 vv = *(const s16x8*)(myL + rl * 72 + cl);
    int rowg = m0 + wm * 64 + rl;
    int colg = n0 + wn * 64 + cl;
    if (EPI == 2) {
      *(s16x8*)(outb + (size_t)rowg * Nout + colg) = vv;
    } else {  // EPI 3: qkv split
      if (colg < 256) {
        *(s16x8*)(outb + (size_t)rowg * 256 + colg) = vv;
      } else {
        unsigned w0 = __builtin_amdgcn_cvt_pk_fp8_f32(b2f(vv[0]), b2f(vv[1]), 0, false);
        w0 = __builtin_amdgcn_cvt_pk_fp8_f32(b2f(vv[2]), b2f(vv[3]), w0, true);
        unsigned w1 = __builtin_amdgcn_cvt_pk_fp8_f32(b2f(vv[4]), b2f(vv[5]), 0, false);
        w1 = __builtin_amdgcn_cvt_pk_fp8_f32(b2f(vv[6]), b2f(vv[7]), w1, true);
        int2 pk = make_int2((int)w0, (int)w1);
        uchar* dst = (colg < 512) ? (k8 + (size_t)rowg * 256 + (colg - 256))
                                  : (v8 + (size_t)rowg * 256 + (colg - 512));
        *(int2*)dst = pk;
      }
    }
  }
}

extern "C" void kernel_launch(void* const* d_in, const int* in_sizes, int n_in,
                              void* d_out, int out_size, void* d_ws, size_t ws_size,
                              hipStream_t stream) {
  const float* in_x   = (const float*)d_in[0];
  const int*   knn    = (const int*)d_in[1];
  const float* ln1_g  = (const float*)d_in[2];
  const float* ln1_b  = (const float*)d_in[3];
  const float* w_qkv  = (const float*)d_in[4];
  const float* w_proj = (const float*)d_in[5];
  const float* b_proj = (const float*)d_in[6];
  const float* ln2_g  = (const float*)d_in[7];
  const float* ln2_b  = (const float*)d_in[8];
  const float* w_fc1  = (const float*)d_in[9];
  const float* b_fc1  = (const float*)d_in[10];
  const float* w_fc2  = (const float*)d_in[11];
  const float* b_fc2  = (const float*)d_in[12];

  // Workspace layout (max ~198.3 MB):
  //   xb   [0,  32) MB   bf16 [N][256] residual stream
  //   act  [32, 64) MB   bf16 [N][256] (LN out / attn out)
  //   big  [64,192) MB   bf16 [N][1024] (fc1 out); sub-aliases during attn:
  //     q_bf [64,96)  k8 [96,112)  v8 [112,128)
  //   wT   [192,198.3) MB  transposed bf16 weights
  char* ws = (char*)d_ws;
  short* xb   = (short*)(ws);
  short* act  = (short*)(ws + 33554432);
  short* big  = (short*)(ws + 67108864);
  short* q_bf = big;
  uchar* k8   = (uchar*)(ws + 100663296);
  uchar* v8   = (uchar*)(ws + 117440512);
  short* wT   = (short*)(ws + 201326592);
  short* wqkvT  = wT;                // [L][768][256]
  short* wprojT = wT + 786432;       // [L][256][256]
  short* wfc1T  = wT + 1048576;      // [L][1024][256]
  short* wfc2T  = wT + 2097152;      // [L][256][1024]

  x2bf<<<16384, 256, 0, stream>>>(in_x, xb);
  wcast<<<dim3(768, 4), 256, 0, stream>>>(w_qkv, wqkvT, 256, 768);
  wcast<<<dim3(256, 4), 256, 0, stream>>>(w_proj, wprojT, 256, 256);
  wcast<<<dim3(1024, 4), 256, 0, stream>>>(w_fc1, wfc1T, 256, 1024);
  wcast<<<dim3(1024, 4), 256, 0, stream>>>(w_fc2, wfc2T, 1024, 256);

  for (int i = 0; i < 4; ++i) {
    ln_k<<<16384, 256, 0, stream>>>(xb, ln1_g + i * 256, ln1_b + i * 256, act);
    gemm_k<3, 256><<<3072, 256, 0, stream>>>(
        act, wqkvT + (size_t)i * 196608, nullptr, nullptr, q_bf, nullptr,
        k8, v8, 768, 6);
    attn_k<<<16384, 256, 0, stream>>>(q_bf, k8, v8, knn, act);
    gemm_k<1, 256><<<1024, 256, 0, stream>>>(
        act, wprojT + (size_t)i * 65536, b_proj + i * 256, xb, xb,
        nullptr, nullptr, nullptr, 256, 2);
    ln_k<<<16384, 256, 0, stream>>>(xb, ln2_g + i * 256, ln2_b + i * 256, act);
    gemm_k<2, 256><<<4096, 256, 0, stream>>>(
        act, wfc1T + (size_t)i * 262144, b_fc1 + i * 1024, nullptr, big,
        nullptr, nullptr, nullptr, 1024, 8);
    if (i < 3)
      gemm_k<1, 1024><<<1024, 256, 0, stream>>>(
          big, wfc2T + (size_t)i * 262144, b_fc2 + i * 256, xb, xb,
          nullptr, nullptr, nullptr, 256, 2);
    else
      gemm_k<4, 1024><<<1024, 256, 0, stream>>>(
          big, wfc2T + (size_t)i * 262144, b_fc2 + i * 256, xb, nullptr,
          (float*)d_out, nullptr, nullptr, 256, 2);
  }
}

// Round 16
// 1077.228 us; speedup vs baseline: 3.3712x; 1.0062x over previous
//
#include <hip/hip_runtime.h>

typedef __attribute__((ext_vector_type(4))) float  f32x4;
typedef __attribute__((ext_vector_type(2))) float  f32x2;
typedef __attribute__((ext_vector_type(8))) __bf16 bf16x8;
typedef __attribute__((ext_vector_type(4))) short  s16x4;
typedef __attribute__((ext_vector_type(8))) short  s16x8;
typedef unsigned char uchar;

__device__ __forceinline__ unsigned short f2bf(float f) {
  unsigned u = __builtin_bit_cast(unsigned, f);
  u += 0x7FFFu + ((u >> 16) & 1u);
  return (unsigned short)(u >> 16);
}
__device__ __forceinline__ float b2f(short s) {
  return __builtin_bit_cast(float, (unsigned)((unsigned short)s) << 16);
}
// sigmoid-form gelu: ~4 VALU ops (vs ~12 for tanh-form)
__device__ __forceinline__ float gelu_sig(float v) {
  float t = __expf(-1.702f * v);
  return v * __builtin_amdgcn_rcpf(1.f + t);
}

__device__ __forceinline__ void gload16(const void* g, void* l) {
  __builtin_amdgcn_global_load_lds(
      (const __attribute__((address_space(1))) void*)g,
      (__attribute__((address_space(3))) void*)l, 16, 0, 0);
}

// in_x f32 -> xb bf16 (once)
__global__ __launch_bounds__(256) void x2bf(const float* __restrict__ x,
                                            short* __restrict__ xb) {
  int i = blockIdx.x * 256 + threadIdx.x;
  float4 v = *(const float4*)(x + (size_t)i * 4);
  s16x4 o;
  o[0] = (short)f2bf(v.x);
  o[1] = (short)f2bf(v.y);
  o[2] = (short)f2bf(v.z);
  o[3] = (short)f2bf(v.w);
  *(s16x4*)(xb + (size_t)i * 4) = o;
}

// Transpose + cast weights: W [L][In][Out] f32 -> WT [L][Out][In] bf16
__global__ __launch_bounds__(256) void wcast(const float* __restrict__ W,
                                             short* __restrict__ WT,
                                             int In, int Out) {
  int i = blockIdx.x * 256 + threadIdx.x;
  int lay = blockIdx.y;
  if (i >= In * Out) return;
  const float* w = W + (size_t)lay * In * Out;
  short* wt = WT + (size_t)lay * In * Out;
  int ii = i % In, oo = i / In;
  wt[(size_t)oo * In + ii] = (short)f2bf(w[(size_t)ii * Out + oo]);
}

// LayerNorm over C=256, bf16 in -> bf16 out, one wave per row
__global__ __launch_bounds__(256) void ln_k(const short* __restrict__ xb,
                                            const float* __restrict__ g,
                                            const float* __restrict__ b,
                                            short* __restrict__ out) {
  int row = blockIdx.x * 4 + (threadIdx.x >> 6);
  int l = threadIdx.x & 63;
  const s16x4 vb = *(const s16x4*)(xb + (size_t)row * 256 + l * 4);
  float v0 = b2f(vb[0]), v1 = b2f(vb[1]), v2 = b2f(vb[2]), v3 = b2f(vb[3]);
  float s  = v0 + v1 + v2 + v3;
  float ss = v0 * v0 + v1 * v1 + v2 * v2 + v3 * v3;
#pragma unroll
  for (int o = 32; o >= 1; o >>= 1) {
    s  += __shfl_xor(s, o);
    ss += __shfl_xor(ss, o);
  }
  float mean = s * (1.0f / 256.0f);
  float var  = ss * (1.0f / 256.0f) - mean * mean;
  float rstd = rsqrtf(var + 1e-5f);
  const float4 gg = *(const float4*)(g + l * 4);
  const float4 bb = *(const float4*)(b + l * 4);
  s16x4 o4;
  o4[0] = (short)f2bf((v0 - mean) * rstd * gg.x + bb.x);
  o4[1] = (short)f2bf((v1 - mean) * rstd * gg.y + bb.y);
  o4[2] = (short)f2bf((v2 - mean) * rstd * gg.z + bb.z);
  o4[3] = (short)f2bf((v3 - mean) * rstd * gg.w + bb.w);
  *(s16x4*)(out + (size_t)row * 256 + l * 4) = o4;
}

// KNN attention v2: one wave per point, T14 async-split.
// Issue order: knn -> k (4 loads) -> q -> ALL 16 v prefetches (in flight
// through QK-dot + softmax; vmcnt FIFO keeps them pending).
__global__ __launch_bounds__(256) void attn_k(const short* __restrict__ q_,
                                              const uchar* __restrict__ k8,
                                              const uchar* __restrict__ v8,
                                              const int* __restrict__ knn,
                                              short* __restrict__ out) {
  int n = blockIdx.x * 4 + (threadIdx.x >> 6);
  int l = threadIdx.x & 63;
  int j = l & 15, g = l >> 4;
  int idxj = knn[(size_t)n * 16 + j];
  // k-gather (needed first)
  const uchar* kp = k8 + (size_t)idxj * 256 + g * 64;
  int4 kv0 = *(const int4*)(kp);
  int4 kv1 = *(const int4*)(kp + 16);
  int4 kv2 = *(const int4*)(kp + 32);
  int4 kv3 = *(const int4*)(kp + 48);
  // q (sequential, L2-friendly)
  const short* qp = q_ + (size_t)n * 256 + g * 64;
  s16x8 q0 = *(const s16x8*)(qp);
  s16x8 q1 = *(const s16x8*)(qp + 8);
  s16x8 q2 = *(const s16x8*)(qp + 16);
  s16x8 q3 = *(const s16x8*)(qp + 24);
  s16x8 q4 = *(const s16x8*)(qp + 32);
  s16x8 q5 = *(const s16x8*)(qp + 40);
  s16x8 q6 = *(const s16x8*)(qp + 48);
  s16x8 q7 = *(const s16x8*)(qp + 56);
  // v prefetch for all 16 neighbors (latency hides under QK + softmax)
  int vv[16];
#pragma unroll
  for (int jj = 0; jj < 16; ++jj) {
    int ij = __shfl(idxj, jj);
    vv[jj] = *(const int*)(v8 + (size_t)ij * 256 + l * 4);
  }
  // QK dot
  float partial = 0.f;
  {
    f32x2 a;
    a = __builtin_amdgcn_cvt_pk_f32_fp8(kv0.x, false);
    partial += a[0] * b2f(q0[0]) + a[1] * b2f(q0[1]);
    a = __builtin_amdgcn_cvt_pk_f32_fp8(kv0.x, true);
    partial += a[0] * b2f(q0[2]) + a[1] * b2f(q0[3]);
    a = __builtin_amdgcn_cvt_pk_f32_fp8(kv0.y, false);
    partial += a[0] * b2f(q0[4]) + a[1] * b2f(q0[5]);
    a = __builtin_amdgcn_cvt_pk_f32_fp8(kv0.y, true);
    partial += a[0] * b2f(q0[6]) + a[1] * b2f(q0[7]);
    a = __builtin_amdgcn_cvt_pk_f32_fp8(kv0.z, false);
    partial += a[0] * b2f(q1[0]) + a[1] * b2f(q1[1]);
    a = __builtin_amdgcn_cvt_pk_f32_fp8(kv0.z, true);
    partial += a[0] * b2f(q1[2]) + a[1] * b2f(q1[3]);
    a = __builtin_amdgcn_cvt_pk_f32_fp8(kv0.w, false);
    partial += a[0] * b2f(q1[4]) + a[1] * b2f(q1[5]);
    a = __builtin_amdgcn_cvt_pk_f32_fp8(kv0.w, true);
    partial += a[0] * b2f(q1[6]) + a[1] * b2f(q1[7]);
    a = __builtin_amdgcn_cvt_pk_f32_fp8(kv1.x, false);
    partial += a[0] * b2f(q2[0]) + a[1] * b2f(q2[1]);
    a = __builtin_amdgcn_cvt_pk_f32_fp8(kv1.x, true);
    partial += a[0] * b2f(q2[2]) + a[1] * b2f(q2[3]);
    a = __builtin_amdgcn_cvt_pk_f32_fp8(kv1.y, false);
    partial += a[0] * b2f(q2[4]) + a[1] * b2f(q2[5]);
    a = __builtin_amdgcn_cvt_pk_f32_fp8(kv1.y, true);
    partial += a[0] * b2f(q2[6]) + a[1] * b2f(q2[7]);
    a = __builtin_amdgcn_cvt_pk_f32_fp8(kv1.z, false);
    partial += a[0] * b2f(q3[0]) + a[1] * b2f(q3[1]);
    a = __builtin_amdgcn_cvt_pk_f32_fp8(kv1.z, true);
    partial += a[0] * b2f(q3[2]) + a[1] * b2f(q3[3]);
    a = __builtin_amdgcn_cvt_pk_f32_fp8(kv1.w, false);
    partial += a[0] * b2f(q3[4]) + a[1] * b2f(q3[5]);
    a = __builtin_amdgcn_cvt_pk_f32_fp8(kv1.w, true);
    partial += a[0] * b2f(q3[6]) + a[1] * b2f(q3[7]);
    a = __builtin_amdgcn_cvt_pk_f32_fp8(kv2.x, false);
    partial += a[0] * b2f(q4[0]) + a[1] * b2f(q4[1]);
    a = __builtin_amdgcn_cvt_pk_f32_fp8(kv2.x, true);
    partial += a[0] * b2f(q4[2]) + a[1] * b2f(q4[3]);
    a = __builtin_amdgcn_cvt_pk_f32_fp8(kv2.y, false);
    partial += a[0] * b2f(q4[4]) + a[1] * b2f(q4[5]);
    a = __builtin_amdgcn_cvt_pk_f32_fp8(kv2.y, true);
    partial += a[0] * b2f(q4[6]) + a[1] * b2f(q4[7]);
    a = __builtin_amdgcn_cvt_pk_f32_fp8(kv2.z, false);
    partial += a[0] * b2f(q5[0]) + a[1] * b2f(q5[1]);
    a = __builtin_amdgcn_cvt_pk_f32_fp8(kv2.z, true);
    partial += a[0] * b2f(q5[2]) + a[1] * b2f(q5[3]);
    a = __builtin_amdgcn_cvt_pk_f32_fp8(kv2.w, false);
    partial += a[0] * b2f(q5[4]) + a[1] * b2f(q5[5]);
    a = __builtin_amdgcn_cvt_pk_f32_fp8(kv2.w, true);
    partial += a[0] * b2f(q5[6]) + a[1] * b2f(q5[7]);
    a = __builtin_amdgcn_cvt_pk_f32_fp8(kv3.x, false);
    partial += a[0] * b2f(q6[0]) + a[1] * b2f(q6[1]);
    a = __builtin_amdgcn_cvt_pk_f32_fp8(kv3.x, true);
    partial += a[0] * b2f(q6[2]) + a[1] * b2f(q6[3]);
    a = __builtin_amdgcn_cvt_pk_f32_fp8(kv3.y, false);
    partial += a[0] * b2f(q6[4]) + a[1] * b2f(q6[5]);
    a = __builtin_amdgcn_cvt_pk_f32_fp8(kv3.y, true);
    partial += a[0] * b2f(q6[6]) + a[1] * b2f(q6[7]);
    a = __builtin_amdgcn_cvt_pk_f32_fp8(kv3.z, false);
    partial += a[0] * b2f(q7[0]) + a[1] * b2f(q7[1]);
    a = __builtin_amdgcn_cvt_pk_f32_fp8(kv3.z, true);
    partial += a[0] * b2f(q7[2]) + a[1] * b2f(q7[3]);
    a = __builtin_amdgcn_cvt_pk_f32_fp8(kv3.w, false);
    partial += a[0] * b2f(q7[4]) + a[1] * b2f(q7[5]);
    a = __builtin_amdgcn_cvt_pk_f32_fp8(kv3.w, true);
    partial += a[0] * b2f(q7[6]) + a[1] * b2f(q7[7]);
  }
  partial += __shfl_xor(partial, 16);
  partial += __shfl_xor(partial, 32);
  float score = partial * 0.0625f;  // C^-0.5, C=256
  float mx = score;
#pragma unroll
  for (int o = 1; o < 16; o <<= 1) mx = fmaxf(mx, __shfl_xor(mx, o));
  float e = __expf(score - mx);
  float sum = e;
#pragma unroll
  for (int o = 1; o < 16; o <<= 1) sum += __shfl_xor(sum, o);
  float attn = e / sum;
  float4 o4 = {0.f, 0.f, 0.f, 0.f};
#pragma unroll
  for (int jj = 0; jj < 16; ++jj) {
    float aj = __shfl(attn, jj);
    f32x2 lo = __builtin_amdgcn_cvt_pk_f32_fp8(vv[jj], false);
    f32x2 hi = __builtin_amdgcn_cvt_pk_f32_fp8(vv[jj], true);
    o4.x += aj * lo[0];
    o4.y += aj * lo[1];
    o4.z += aj * hi[0];
    o4.w += aj * hi[1];
  }
  s16x4 ob;
  ob[0] = (short)f2bf(o4.x);
  ob[1] = (short)f2bf(o4.y);
  ob[2] = (short)f2bf(o4.z);
  ob[3] = (short)f2bf(o4.w);
  *(s16x4*)(out + (size_t)n * 256 + l * 4) = ob;
}

// GEMM: A [M][KD] bf16 x BT [Nout][KD] bf16 -> out [M][Nout]
// EPI 1: +bias +resid(bf16) -> bf16 xb.  EPI 4: +bias +resid(bf16) -> f32.
// EPI 2: +bias, sigmoid-gelu -> bf16 (LDS-transpose, s16x8 stores).
// EPI 3: qkv split -> q bf16 / k8 fp8 / v8 fp8 (LDS-transpose epilogue).
// 128x128 tile, BK=64, 4 waves (2x2), T2 XOR swizzle, T1 XCD-chunked swizzle.
template <int EPI, int KD>
__global__ __launch_bounds__(256) void gemm_k(
    const short* __restrict__ A, const short* __restrict__ BT,
    const float* __restrict__ bias, const short* __restrict__ residb,
    short* __restrict__ outb, float* __restrict__ outf,
    uchar* __restrict__ k8, uchar* __restrict__ v8, int Nout, int gx) {
  __shared__ __align__(16) char pool[36864];
  short* lA = (short*)pool;
  short* lB = (short*)(pool + 16384);
  const int tid = threadIdx.x;
  const int l = tid & 63, w = tid >> 6;
  const int nwg = gridDim.x;
  const int bid = blockIdx.x;
  const int swz = (bid & 7) * (nwg >> 3) + (bid >> 3);
  const int m0 = (swz / gx) << 7, n0 = (swz % gx) << 7;
  const int wm = w >> 1, wn = w & 1;

  f32x4 acc[4][4];
#pragma unroll
  for (int i = 0; i < 4; ++i)
#pragma unroll
    for (int jj = 0; jj < 4; ++jj) acc[i][jj] = f32x4{0.f, 0.f, 0.f, 0.f};

  const int srow = (w << 3) + (l >> 3);
  const int scol = (((l & 7) << 3)) ^ ((srow & 7) << 3);
  const short* gA = A + (size_t)(m0 + srow) * KD + scol;
  const short* gB = BT + (size_t)(n0 + srow) * KD + scol;

  for (int kt = 0; kt < KD; kt += 64) {
#pragma unroll
    for (int it = 0; it < 4; ++it) {
      gload16(gA + (size_t)(it * 32) * KD + kt, &lA[(it * 32 + w * 8) * 64]);
      gload16(gB + (size_t)(it * 32) * KD + kt, &lB[(it * 32 + w * 8) * 64]);
    }
    __syncthreads();
#pragma unroll
    for (int kc = 0; kc < 2; ++kc) {
      bf16x8 aF[4], bF[4];
#pragma unroll
      for (int f = 0; f < 4; ++f) {
        int r = wm * 64 + f * 16 + (l & 15);
        int ce = (kc * 32 + ((l >> 4) << 3)) ^ ((r & 7) << 3);
        aF[f] = *(const bf16x8*)(lA + r * 64 + ce);
      }
#pragma unroll
      for (int f = 0; f < 4; ++f) {
        int r = wn * 64 + f * 16 + (l & 15);
        int ce = (kc * 32 + ((l >> 4) << 3)) ^ ((r & 7) << 3);
        bF[f] = *(const bf16x8*)(lB + r * 64 + ce);
      }
#pragma unroll
      for (int mf = 0; mf < 4; ++mf)
#pragma unroll
        for (int nf = 0; nf < 4; ++nf)
          acc[mf][nf] = __builtin_amdgcn_mfma_f32_16x16x32_bf16(
              aF[mf], bF[nf], acc[mf][nf], 0, 0, 0);
    }
    __syncthreads();
  }

  const int lr = (l >> 4) << 2, lc = l & 15;
  if (EPI == 1 || EPI == 4) {
#pragma unroll
    for (int mf = 0; mf < 4; ++mf) {
#pragma unroll
      for (int nf = 0; nf < 4; ++nf) {
#pragma unroll
        for (int jj = 0; jj < 4; ++jj) {
          int row = m0 + wm * 64 + mf * 16 + lr + jj;
          int col = n0 + wn * 64 + nf * 16 + lc;
          float v = acc[mf][nf][jj] + bias[col] +
                    b2f(residb[(size_t)row * 256 + col]);
          if (EPI == 1)
            outb[(size_t)row * 256 + col] = (short)f2bf(v);
          else
            outf[(size_t)row * 256 + col] = v;
        }
      }
    }
    return;
  }

  // EPI 2/3: wave-private LDS transpose -> coalesced stores.
  short* myL = (short*)(pool + w * 9216);
#pragma unroll
  for (int mf = 0; mf < 4; ++mf) {
#pragma unroll
    for (int nf = 0; nf < 4; ++nf) {
#pragma unroll
      for (int jj = 0; jj < 4; ++jj) {
        int rl = mf * 16 + lr + jj;
        int cl = nf * 16 + lc;
        float v = acc[mf][nf][jj];
        if (EPI == 2) v = gelu_sig(v + bias[n0 + wn * 64 + cl]);
        myL[rl * 72 + cl] = (short)f2bf(v);
      }
    }
  }
#pragma unroll
  for (int it = 0; it < 8; ++it) {
    int rl = it * 8 + (l >> 3);
    int cl = (l & 7) * 8;
    s16x8 vv = *(const s16x8*)(myL + rl * 72 + cl);
    int rowg = m0 + wm * 64 + rl;
    int colg = n0 + wn * 64 + cl;
    if (EPI == 2) {
      *(s16x8*)(outb + (size_t)rowg * Nout + colg) = vv;
    } else {  // EPI 3: qkv split
      if (colg < 256) {
        *(s16x8*)(outb + (size_t)rowg * 256 + colg) = vv;
      } else {
        unsigned w0 = __builtin_amdgcn_cvt_pk_fp8_f32(b2f(vv[0]), b2f(vv[1]), 0, false);
        w0 = __builtin_amdgcn_cvt_pk_fp8_f32(b2f(vv[2]), b2f(vv[3]), w0, true);
        unsigned w1 = __builtin_amdgcn_cvt_pk_fp8_f32(b2f(vv[4]), b2f(vv[5]), 0, false);
        w1 = __builtin_amdgcn_cvt_pk_fp8_f32(b2f(vv[6]), b2f(vv[7]), w1, true);
        int2 pk = make_int2((int)w0, (int)w1);
        uchar* dst = (colg < 512) ? (k8 + (size_t)rowg * 256 + (colg - 256))
                                  : (v8 + (size_t)rowg * 256 + (colg - 512));
        *(int2*)dst = pk;
      }
    }
  }
}

extern "C" void kernel_launch(void* const* d_in, const int* in_sizes, int n_in,
                              void* d_out, int out_size, void* d_ws, size_t ws_size,
                              hipStream_t stream) {
  const float* in_x   = (const float*)d_in[0];
  const int*   knn    = (const int*)d_in[1];
  const float* ln1_g  = (const float*)d_in[2];
  const float* ln1_b  = (const float*)d_in[3];
  const float* w_qkv  = (const float*)d_in[4];
  const float* w_proj = (const float*)d_in[5];
  const float* b_proj = (const float*)d_in[6];
  const float* ln2_g  = (const float*)d_in[7];
  const float* ln2_b  = (const float*)d_in[8];
  const float* w_fc1  = (const float*)d_in[9];
  const float* b_fc1  = (const float*)d_in[10];
  const float* w_fc2  = (const float*)d_in[11];
  const float* b_fc2  = (const float*)d_in[12];

  // Workspace layout (max ~198.3 MB):
  //   xb   [0,  32) MB   bf16 [N][256] residual stream
  //   act  [32, 64) MB   bf16 [N][256] (LN out / attn out)
  //   big  [64,192) MB   bf16 [N][1024] (fc1 out); sub-aliases during attn:
  //     q_bf [64,96)  k8 [96,112)  v8 [112,128)
  //   wT   [192,198.3) MB  transposed bf16 weights
  char* ws = (char*)d_ws;
  short* xb   = (short*)(ws);
  short* act  = (short*)(ws + 33554432);
  short* big  = (short*)(ws + 67108864);
  short* q_bf = big;
  uchar* k8   = (uchar*)(ws + 100663296);
  uchar* v8   = (uchar*)(ws + 117440512);
  short* wT   = (short*)(ws + 201326592);
  short* wqkvT  = wT;                // [L][768][256]
  short* wprojT = wT + 786432;       // [L][256][256]
  short* wfc1T  = wT + 1048576;      // [L][1024][256]
  short* wfc2T  = wT + 2097152;      // [L][256][1024]

  x2bf<<<16384, 256, 0, stream>>>(in_x, xb);
  wcast<<<dim3(768, 4), 256, 0, stream>>>(w_qkv, wqkvT, 256, 768);
  wcast<<<dim3(256, 4), 256, 0, stream>>>(w_proj, wprojT, 256, 256);
  wcast<<<dim3(1024, 4), 256, 0, stream>>>(w_fc1, wfc1T, 256, 1024);
  wcast<<<dim3(1024, 4), 256, 0, stream>>>(w_fc2, wfc2T, 1024, 256);

  for (int i = 0; i < 4; ++i) {
    ln_k<<<16384, 256, 0, stream>>>(xb, ln1_g + i * 256, ln1_b + i * 256, act);
    gemm_k<3, 256><<<3072, 256, 0, stream>>>(
        act, wqkvT + (size_t)i * 196608, nullptr, nullptr, q_bf, nullptr,
        k8, v8, 768, 6);
    attn_k<<<16384, 256, 0, stream>>>(q_bf, k8, v8, knn, act);
    gemm_k<1, 256><<<1024, 256, 0, stream>>>(
        act, wprojT + (size_t)i * 65536, b_proj + i * 256, xb, xb,
        nullptr, nullptr, nullptr, 256, 2);
    ln_k<<<16384, 256, 0, stream>>>(xb, ln2_g + i * 256, ln2_b + i * 256, act);
    gemm_k<2, 256><<<4096, 256, 0, stream>>>(
        act, wfc1T + (size_t)i * 262144, b_fc1 + i * 1024, nullptr, big,
        nullptr, nullptr, nullptr, 1024, 8);
    if (i < 3)
      gemm_k<1, 1024><<<1024, 256, 0, stream>>>(
          big, wfc2T + (size_t)i * 262144, b_fc2 + i * 256, xb, xb,
          nullptr, nullptr, nullptr, 256, 2);
    else
      gemm_k<4, 1024><<<1024, 256, 0, stream>>>(
          big, wfc2T + (size_t)i * 262144, b_fc2 + i * 256, xb, nullptr,
          (float*)d_out, nullptr, nullptr, 256, 2);
  }
}